// Round 10
// baseline (79.252 us; speedup 1.0000x reference)
//
#include <hip/hip_runtime.h>

#define NMOL   32
#define NATOM  512
#define NPAIR  32768
#define NB     64
#define HIDDEN 256
#define TOTNATOM (NMOL * NATOM)
#define NSUB   8
#define CAP8   16   // records per (atom, sub-block): lambda~2.1, P(>=16)~1e-9
#define ABLK   8    // atoms per gathernn block
#define NGNN   (TOTNATOM / ABLK)   // 2048 blocks

// ---------------------------------------------------------------------------
// K1 scatter: 256 blocks (mol x sub) x 1024 thr, 4 pairs/thread.
// cart+species staged in LDS (R10: kills ~6 dependent L2 gathers/pair).
// LDS-private counters -> per-block record segments; zero cross-XCD atomics.
// ---------------------------------------------------------------------------
__global__ __launch_bounds__(1024) void scatter_kernel(
    const float* __restrict__ cart, const float* __restrict__ shifts,
    const int* __restrict__ species, const int* __restrict__ atom_index,
    unsigned* __restrict__ cnt8, float2* __restrict__ rec,
    float* __restrict__ tv_part)
{
    __shared__ float    tv_sc[NATOM * 3];   // 6 KB
    __shared__ float    s_cart[NATOM * 3];  // 6 KB
    __shared__ int      s_sp[NATOM];        // 2 KB
    __shared__ unsigned lcnt[NATOM];        // 2 KB
    const int tid = threadIdx.x;
    const int b   = blockIdx.x;
    const int mol = b >> 3;
    const int sub = b & 7;

    const float* cm = cart + (size_t)mol * NATOM * 3;
    const int*   sp = species + (size_t)mol * NATOM;
    for (int i = tid; i < NATOM * 3; i += 1024) { tv_sc[i] = 0.f; s_cart[i] = cm[i]; }
    if (tid < NATOM) { lcnt[tid] = 0u; s_sp[tid] = sp[tid]; }
    __syncthreads();

    const int* ai0 = atom_index + (size_t)mol * NPAIR;
    const int* ai1 = ai0 + (size_t)NMOL * NPAIR;
    const float* sh = shifts + (size_t)mol * NPAIR * 3;
    const int base = sub * 4096;

#pragma unroll
    for (int k = 0; k < 4; ++k) {
        const int p  = base + k * 1024 + tid;
        const int i0 = ai0[p];
        const int i1 = ai1[p];
        const float sx = sh[p * 3 + 0], sy = sh[p * 3 + 1], sz = sh[p * 3 + 2];
        if (!(sx > -1e10f && sy > -1e10f && sz > -1e10f)) continue;  // masked
        const float dx = s_cart[i0 * 3 + 0] - s_cart[i1 * 3 + 0] + sx;
        const float dy = s_cart[i0 * 3 + 1] - s_cart[i1 * 3 + 1] + sy;
        const float dz = s_cart[i0 * 3 + 2] - s_cart[i1 * 3 + 2] + sz;
        unsafeAtomicAdd(&tv_sc[i0 * 3 + 0], dx);        // ds_add_f32
        unsafeAtomicAdd(&tv_sc[i0 * 3 + 1], dy);
        unsafeAtomicAdd(&tv_sc[i0 * 3 + 2], dz);
        const float d = sqrtf(dx * dx + dy * dy + dz * dz + 1e-12f);
        if (d < 5.0f) {
            const float fc = 0.5f * (__cosf(0.62831853071795864769f * d) + 1.f);
            // pack spc into fc's low 3 mantissa bits (<=2^-20 rel perturbation)
            const unsigned fb = (__float_as_uint(fc) & ~7u) | (unsigned)s_sp[i1];
            const unsigned pos = atomicAdd(&lcnt[i0], 1u);   // LDS, native
            if (pos < CAP8)
                rec[((size_t)b * NATOM + i0) * CAP8 + pos] =
                    make_float2(d, __uint_as_float(fb));
        }
    }
    __syncthreads();

    if (tid < NATOM) cnt8[((size_t)mol * NATOM + tid) * NSUB + sub] = lcnt[tid];
    float* tg = tv_part + (size_t)b * NATOM * 3;
    for (int i = tid; i < NATOM * 3; i += 1024) tg[i] = tv_sc[i];
}

// ---------------------------------------------------------------------------
// K2 gather+nn: 2048 blocks x 256 thr (R10: was 1024 blocks -> 4 waves/SIMD,
// occupancy 31%, 85% stall; now 8 blocks/CU -> up to 32 waves/CU).
// Gather: 16 tasks = (atom 0..7, bucket-half 0..1), wave takes 4 tasks ->
// halves the serial bucket chain. Partials combined in LDS after barrier.
// NN: thread = hidden unit, 8 atoms from LDS, float4 LDS rows.
// ---------------------------------------------------------------------------
__global__ __launch_bounds__(256, 4) void gathernn_kernel(
    const unsigned* __restrict__ cnt8, const float2* __restrict__ rec,
    const float* __restrict__ centers, const float* __restrict__ widths,
    const float* __restrict__ c_emb, const float* __restrict__ tv_part,
    const float* __restrict__ W1, const float* __restrict__ b1,
    const float* __restrict__ W2, const float* __restrict__ b2,
    float* __restrict__ dip_part)
{
    __shared__ float cemb[8 * NB];          // 2 KB
    __shared__ float dens_l[ABLK][2][NB];   // 4 KB (two half-partials per atom)
    __shared__ float tv_l[ABLK * 3];
    __shared__ float part_l[4][ABLK];

    const int tid  = threadIdx.x;
    const int lane = tid & 63;
    const int wave = tid >> 6;
    const int a0   = blockIdx.x * ABLK;         // global atom base
    const int mol  = a0 >> 9;

    for (int i = tid; i < 8 * NB; i += 256) cemb[i] = c_emb[i];
    __syncthreads();

    // ---- gather: 16 (atom, half) tasks over 4 waves ----
    {
        const float cb  = centers[lane];
        const float nwb = -widths[lane];

        for (int t = wave; t < 2 * ABLK; t += 4) {
            const int al = t >> 1;              // local atom
            const int hf = t & 1;               // bucket half (subs 4hf..4hf+3)
            const int a  = a0 + al;
            const int ra = a & 511;
            const unsigned* cp = cnt8 + (size_t)a * NSUB + hf * 4;
            float acc = 0.f;
#pragma unroll
            for (int s = 0; s < 4; ++s) {
                const int n = min((int)cp[s], CAP8);
                const float2* r = rec +
                    ((size_t)(mol * NSUB + hf * 4 + s) * NATOM + ra) * CAP8;
                int k = 0;
                for (; k + 2 <= n; k += 2) {
                    const float2 r0 = r[k], r1 = r[k + 1];
                    const unsigned f0 = __float_as_uint(r0.y), f1 = __float_as_uint(r1.y);
                    const float t0 = r0.x - cb, t1 = r1.x - cb;
                    acc = fmaf(__expf(nwb * t0 * t0) * __uint_as_float(f0 & ~7u),
                               cemb[((f0 & 7u) << 6) | lane], acc);
                    acc = fmaf(__expf(nwb * t1 * t1) * __uint_as_float(f1 & ~7u),
                               cemb[((f1 & 7u) << 6) | lane], acc);
                }
                if (k < n) {
                    const float2 r0 = r[k];
                    const unsigned f0 = __float_as_uint(r0.y);
                    const float t0 = r0.x - cb;
                    acc = fmaf(__expf(nwb * t0 * t0) * __uint_as_float(f0 & ~7u),
                               cemb[((f0 & 7u) << 6) | lane], acc);
                }
            }
            dens_l[al][hf][lane] = acc;
        }
        // tv: 8 atoms x 3 comps, sum 8 block-partials each
        if (tid < ABLK * 3) {
            const int al = tid / 3, c = tid - al * 3;
            const int ra = (a0 + al) & 511;
            float s = 0.f;
#pragma unroll
            for (int sb = 0; sb < NSUB; ++sb)
                s += tv_part[((size_t)(mol * NSUB + sb) * NATOM + ra) * 3 + c];
            tv_l[al * 3 + c] = s;
        }
    }
    __syncthreads();
    // combine the two half-partials
    for (int i = tid; i < ABLK * NB; i += 256) {
        const int al = i >> 6, l = i & 63;
        dens_l[al][0][l] += dens_l[al][1][l];
    }
    __syncthreads();

    // ---- nn ----
    {
        const int j = tid;                      // hidden unit 0..255
        float w1r[64];
#pragma unroll
        for (int q = 0; q < 64; ++q) w1r[q] = W1[q * HIDDEN + j];
        const float b1v = b1[j];
        const float w2v = W2[j];

#pragma unroll
        for (int a = 0; a < ABLK; ++a) {
            const float4* row4 = reinterpret_cast<const float4*>(dens_l[a][0]);
            float h0 = b1v, h1 = 0.f, h2 = 0.f, h3 = 0.f;
#pragma unroll
            for (int q = 0; q < 16; ++q) {      // ds_read_b128 broadcast
                const float4 v = row4[q];
                h0 = fmaf(v.x, w1r[q * 4 + 0], h0);
                h1 = fmaf(v.y, w1r[q * 4 + 1], h1);
                h2 = fmaf(v.z, w1r[q * 4 + 2], h2);
                h3 = fmaf(v.w, w1r[q * 4 + 3], h3);
            }
            const float h = (h0 + h1) + (h2 + h3);
            float con = (h / (1.f + __expf(-h))) * w2v;   // silu * W2
#pragma unroll
            for (int off = 32; off; off >>= 1) con += __shfl_down(con, off);
            if (lane == 0) part_l[wave][a] = con;
        }
        __syncthreads();

        if (tid < ABLK) {
            const int a = tid;
            const float out = part_l[0][a] + part_l[1][a]
                            + part_l[2][a] + part_l[3][a] + b2[0];
            float px = out * tv_l[a * 3 + 0];
            float py = out * tv_l[a * 3 + 1];
            float pz = out * tv_l[a * 3 + 2];
#pragma unroll
            for (int off = 4; off; off >>= 1) {
                px += __shfl_down(px, off, 8);
                py += __shfl_down(py, off, 8);
                pz += __shfl_down(pz, off, 8);
            }
            if (a == 0) {
                dip_part[blockIdx.x * 3 + 0] = px;   // plain store, no atomics
                dip_part[blockIdx.x * 3 + 1] = py;
                dip_part[blockIdx.x * 3 + 2] = pz;
            }
        }
    }
}

// ---------------------------------------------------------------------------
// K3 dipfinal: reduce 64 block-partials per molecule (96 outputs).
// ---------------------------------------------------------------------------
__global__ __launch_bounds__(128) void dipfinal_kernel(
    const float* __restrict__ dip_part, float* __restrict__ dipole)
{
    const int t = threadIdx.x;
    if (t < NMOL * 3) {
        const int m = t / 3, c = t - m * 3;
        const int bpm = NGNN / NMOL;            // 64 blocks per molecule
        float s = 0.f;
        for (int k = 0; k < bpm; ++k) s += dip_part[(m * bpm + k) * 3 + c];
        dipole[t] = s;
    }
}

// ---------------------------------------------------------------------------
extern "C" void kernel_launch(void* const* d_in, const int* in_sizes, int n_in,
                              void* d_out, int out_size, void* d_ws, size_t ws_size,
                              hipStream_t stream)
{
    const float* cart       = (const float*)d_in[0];
    const float* shifts     = (const float*)d_in[1];
    const float* centers    = (const float*)d_in[2];
    const float* widths     = (const float*)d_in[3];
    const float* c_emb      = (const float*)d_in[4];
    const float* W1         = (const float*)d_in[5];
    const float* b1         = (const float*)d_in[6];
    const float* W2         = (const float*)d_in[7];
    const float* b2         = (const float*)d_in[8];
    const int*   species    = (const int*)d_in[10];
    const int*   atom_index = (const int*)d_in[11];

    // ws: tv_part(1.5MB) | cnt8(512KB) | dip_part(24KB) | rec(16MB)
    float*    tv_part  = (float*)d_ws;
    unsigned* cnt8     = (unsigned*)(tv_part + (size_t)NMOL * NSUB * NATOM * 3);
    float*    dip_part = (float*)(cnt8 + (size_t)TOTNATOM * NSUB);
    float2*   rec      = (float2*)(dip_part + (size_t)NGNN * 3);
    float*    dipole   = (float*)d_out;

    hipLaunchKernelGGL(scatter_kernel, dim3(NMOL * NSUB), dim3(1024), 0, stream,
                       cart, shifts, species, atom_index, cnt8, rec, tv_part);
    hipLaunchKernelGGL(gathernn_kernel, dim3(NGNN), dim3(256), 0, stream,
                       cnt8, rec, centers, widths, c_emb, tv_part,
                       W1, b1, W2, b2, dip_part);
    hipLaunchKernelGGL(dipfinal_kernel, dim3(1), dim3(128), 0, stream,
                       dip_part, dipole);
}

// Round 11
// 62.743 us; speedup vs baseline: 1.2631x; 1.2631x over previous
//
#include <hip/hip_runtime.h>

#define NMOL   32
#define NATOM  512
#define NPAIR  32768
#define NB     64
#define HIDDEN 256
#define TOTNATOM (NMOL * NATOM)
#define NSUB   8
#define CAP8   16    // records per (atom, sub-block)
#define ABLK   8     // atoms per gather block
#define SLOTS  128   // LDS record slots per atom (>= 8*CAP8)

// ---------------------------------------------------------------------------
// K1 scatter: 256 blocks (mol x sub) x 1024 thr, 4 pairs/thread. Unchanged R10.
// ---------------------------------------------------------------------------
__global__ __launch_bounds__(1024) void scatter_kernel(
    const float* __restrict__ cart, const float* __restrict__ shifts,
    const int* __restrict__ species, const int* __restrict__ atom_index,
    unsigned* __restrict__ cnt8, float2* __restrict__ rec,
    float* __restrict__ tv_part)
{
    __shared__ float    tv_sc[NATOM * 3];   // 6 KB
    __shared__ float    s_cart[NATOM * 3];  // 6 KB
    __shared__ int      s_sp[NATOM];        // 2 KB
    __shared__ unsigned lcnt[NATOM];        // 2 KB
    const int tid = threadIdx.x;
    const int b   = blockIdx.x;
    const int mol = b >> 3;
    const int sub = b & 7;

    const float* cm = cart + (size_t)mol * NATOM * 3;
    const int*   sp = species + (size_t)mol * NATOM;
    for (int i = tid; i < NATOM * 3; i += 1024) { tv_sc[i] = 0.f; s_cart[i] = cm[i]; }
    if (tid < NATOM) { lcnt[tid] = 0u; s_sp[tid] = sp[tid]; }
    __syncthreads();

    const int* ai0 = atom_index + (size_t)mol * NPAIR;
    const int* ai1 = ai0 + (size_t)NMOL * NPAIR;
    const float* sh = shifts + (size_t)mol * NPAIR * 3;
    const int base = sub * 4096;

#pragma unroll
    for (int k = 0; k < 4; ++k) {
        const int p  = base + k * 1024 + tid;
        const int i0 = ai0[p];
        const int i1 = ai1[p];
        const float sx = sh[p * 3 + 0], sy = sh[p * 3 + 1], sz = sh[p * 3 + 2];
        if (!(sx > -1e10f && sy > -1e10f && sz > -1e10f)) continue;  // masked
        const float dx = s_cart[i0 * 3 + 0] - s_cart[i1 * 3 + 0] + sx;
        const float dy = s_cart[i0 * 3 + 1] - s_cart[i1 * 3 + 1] + sy;
        const float dz = s_cart[i0 * 3 + 2] - s_cart[i1 * 3 + 2] + sz;
        unsafeAtomicAdd(&tv_sc[i0 * 3 + 0], dx);        // ds_add_f32
        unsafeAtomicAdd(&tv_sc[i0 * 3 + 1], dy);
        unsafeAtomicAdd(&tv_sc[i0 * 3 + 2], dz);
        const float d = sqrtf(dx * dx + dy * dy + dz * dz + 1e-12f);
        if (d < 5.0f) {
            const float fc = 0.5f * (__cosf(0.62831853071795864769f * d) + 1.f);
            // pack spc into fc's low 3 mantissa bits (<=2^-20 rel perturbation)
            const unsigned fb = (__float_as_uint(fc) & ~7u) | (unsigned)s_sp[i1];
            const unsigned pos = atomicAdd(&lcnt[i0], 1u);   // LDS, native
            if (pos < CAP8)
                rec[((size_t)b * NATOM + i0) * CAP8 + pos] =
                    make_float2(d, __uint_as_float(fb));
        }
    }
    __syncthreads();

    if (tid < NATOM) cnt8[((size_t)mol * NATOM + tid) * NSUB + sub] = lcnt[tid];
    float* tg = tv_part + (size_t)b * NATOM * 3;
    for (int i = tid; i < NATOM * 3; i += 1024) tg[i] = tv_sc[i];
}

// ---------------------------------------------------------------------------
// K2 gather: 2048 blocks x 256 thr, 8 atoms/block.
// R11: PARALLEL segment fetch -- 64 threads each copy one (atom,sub) segment
// into LDS concurrently (one ~400cy latency hit instead of R9/R10's serial
// 8-segment dependent chain per wave). Compute: wave=2 atoms, lane=basis,
// float4-chunked LDS stream (records zero-padded to x8).
// ---------------------------------------------------------------------------
__global__ __launch_bounds__(256) void gather_kernel(
    const unsigned* __restrict__ cnt8, const float2* __restrict__ rec,
    const float* __restrict__ centers, const float* __restrict__ widths,
    const float* __restrict__ c_emb, const float* __restrict__ tv_part,
    float* __restrict__ dens, float* __restrict__ tvv)
{
    __shared__ float    cemb[8 * NB];          // 2 KB
    __shared__ float2   list[ABLK][SLOTS];     // 8 KB
    __shared__ unsigned scnt[ABLK][NSUB];
    __shared__ unsigned soff[ABLK][NSUB];
    __shared__ unsigned mtot[ABLK];

    const int tid = threadIdx.x;
    const int a0  = blockIdx.x * ABLK;
    const int mol = a0 >> 9;
    const int ra0 = a0 & 511;

    for (int i = tid; i < 8 * NB; i += 256) cemb[i] = c_emb[i];
    if (tid < ABLK * NSUB) {
        const int al = tid >> 3, s = tid & 7;
        scnt[al][s] = cnt8[(size_t)(a0 + al) * NSUB + s];   // coalesced
    }
    __syncthreads();

    if (tid < ABLK) {    // per-atom prefix over 8 segment counts + zero-pad
        unsigned o = 0;
#pragma unroll
        for (int s = 0; s < NSUB; ++s) {
            soff[tid][s] = o;
            o += min(scnt[tid][s], (unsigned)CAP8);
        }
        const unsigned mp = (o + 7u) & ~7u;    // pad to multiple of 8
        mtot[tid] = mp;
        for (unsigned k = o; k < mp; ++k) list[tid][k] = make_float2(0.f, 0.f);
    }
    __syncthreads();

    if (tid < ABLK * NSUB) {                   // 64 parallel segment copies
        const int al = tid >> 3, s = tid & 7;
        const int n = (int)min(scnt[al][s], (unsigned)CAP8);
        const float2* src = rec + ((size_t)(mol * NSUB + s) * NATOM + (ra0 + al)) * CAP8;
        float2* dst = &list[al][soff[al][s]];
        for (int k = 0; k < n; ++k) dst[k] = src[k];
    }
    __syncthreads();

    const int lane = tid & 63;
    const int wave = tid >> 6;
    const float cb   = centers[lane];
    const float nwb2 = -widths[lane] * 1.4426950408889634f;   // fold log2(e)

#define REC1(dv, fv) { const unsigned f_ = __float_as_uint(fv);              \
        const float t_ = (dv) - cb;                                          \
        acc = fmaf(exp2f(nwb2 * t_ * t_) * __uint_as_float(f_ & ~7u),        \
                   cemb[((f_ & 7u) << 6) | lane], acc); }

    for (int al = wave; al < ABLK; al += 4) {  // wave handles 2 atoms
        const int m = (int)mtot[al];
        const float4* l4 = reinterpret_cast<const float4*>(list[al]);
        float acc = 0.f;
        for (int j = 0; j < m; j += 8) {       // 8 records per chunk
            const float4 q0 = l4[(j >> 1) + 0];
            const float4 q1 = l4[(j >> 1) + 1];
            const float4 q2 = l4[(j >> 1) + 2];
            const float4 q3 = l4[(j >> 1) + 3];
            REC1(q0.x, q0.y) REC1(q0.z, q0.w)
            REC1(q1.x, q1.y) REC1(q1.z, q1.w)
            REC1(q2.x, q2.y) REC1(q2.z, q2.w)
            REC1(q3.x, q3.y) REC1(q3.z, q3.w)
        }
        dens[(size_t)(a0 + al) * NB + lane] = acc;
    }
#undef REC1

    if (tid < ABLK * 3) {                      // tv: sum the 8 block-partials
        const int al = tid / 3, c = tid - al * 3;
        float s = 0.f;
#pragma unroll
        for (int sb = 0; sb < NSUB; ++sb)
            s += tv_part[((size_t)(mol * NSUB + sb) * NATOM + (ra0 + al)) * 3 + c];
        tvv[(size_t)(a0 + al) * 3 + c] = s;
    }
}

// ---------------------------------------------------------------------------
// K3 nn: standalone again (R5 structure). Plain __launch_bounds__(256): the
// (256,4) hint in R9/R10 made the compiler target 8 waves/EU -> 52 VGPR ->
// w1r[64] demoted to per-atom W1 re-loads (~1 GB L2 traffic, the 40us wall).
// Unbounded, w1r stays register-resident (~100 VGPR, 4 waves/EU).
// ---------------------------------------------------------------------------
__global__ __launch_bounds__(256) void nn_kernel(
    const float* __restrict__ dens, const float* __restrict__ tv,
    const float* __restrict__ W1, const float* __restrict__ b1,
    const float* __restrict__ W2, const float* __restrict__ b2,
    float* __restrict__ dip_part)
{
    const int j    = threadIdx.x;             // hidden unit 0..255
    const int lane = j & 63;
    const int wave = j >> 6;
    const int a0   = blockIdx.x * 16;         // global atom base

    float w1r[64];
#pragma unroll
    for (int q = 0; q < 64; ++q) w1r[q] = W1[q * HIDDEN + j];
    const float b1v = b1[j];
    const float w2v = W2[j];

    float con[16];
#pragma unroll
    for (int a = 0; a < 16; ++a) {
        const float* row = dens + (size_t)(a0 + a) * NB;   // block-uniform
        float h0 = b1v, h1 = 0.f, h2 = 0.f, h3 = 0.f;
#pragma unroll
        for (int q = 0; q < 64; q += 4) {
            h0 = fmaf(row[q + 0], w1r[q + 0], h0);
            h1 = fmaf(row[q + 1], w1r[q + 1], h1);
            h2 = fmaf(row[q + 2], w1r[q + 2], h2);
            h3 = fmaf(row[q + 3], w1r[q + 3], h3);
        }
        const float h = (h0 + h1) + (h2 + h3);
        con[a] = (h / (1.f + __expf(-h))) * w2v;           // silu * W2
    }

    __shared__ float part[4][16];
#pragma unroll
    for (int a = 0; a < 16; ++a) {
        float v = con[a];
#pragma unroll
        for (int off = 32; off; off >>= 1) v += __shfl_down(v, off);
        if (lane == 0) part[wave][a] = v;
    }
    __syncthreads();

    if (j < 16) {
        const int a = j;
        const float out = part[0][a] + part[1][a] + part[2][a] + part[3][a] + b2[0];
        const float* tvp = tv + (size_t)(a0 + a) * 3;
        float px = out * tvp[0], py = out * tvp[1], pz = out * tvp[2];
#pragma unroll
        for (int off = 8; off; off >>= 1) {
            px += __shfl_down(px, off, 16);
            py += __shfl_down(py, off, 16);
            pz += __shfl_down(pz, off, 16);
        }
        if (a == 0) {
            dip_part[blockIdx.x * 3 + 0] = px;   // plain store, no atomics
            dip_part[blockIdx.x * 3 + 1] = py;
            dip_part[blockIdx.x * 3 + 2] = pz;
        }
    }
}

// ---------------------------------------------------------------------------
// K4 dipfinal: reduce 32 nn-block partials per molecule.
// ---------------------------------------------------------------------------
__global__ __launch_bounds__(128) void dipfinal_kernel(
    const float* __restrict__ dip_part, float* __restrict__ dipole)
{
    const int t = threadIdx.x;
    if (t < NMOL * 3) {
        const int m = t / 3, c = t - m * 3;
        float s = 0.f;
#pragma unroll
        for (int k = 0; k < 32; ++k) s += dip_part[(m * 32 + k) * 3 + c];
        dipole[t] = s;
    }
}

// ---------------------------------------------------------------------------
extern "C" void kernel_launch(void* const* d_in, const int* in_sizes, int n_in,
                              void* d_out, int out_size, void* d_ws, size_t ws_size,
                              hipStream_t stream)
{
    const float* cart       = (const float*)d_in[0];
    const float* shifts     = (const float*)d_in[1];
    const float* centers    = (const float*)d_in[2];
    const float* widths     = (const float*)d_in[3];
    const float* c_emb      = (const float*)d_in[4];
    const float* W1         = (const float*)d_in[5];
    const float* b1         = (const float*)d_in[6];
    const float* W2         = (const float*)d_in[7];
    const float* b2         = (const float*)d_in[8];
    const int*   species    = (const int*)d_in[10];
    const int*   atom_index = (const int*)d_in[11];

    // ws: tv_part(1.5MB) | cnt8(512KB) | dens(4MB) | tvv(192KB) | dip(12KB) | rec(16MB)
    float*    tv_part  = (float*)d_ws;
    unsigned* cnt8     = (unsigned*)(tv_part + (size_t)NMOL * NSUB * NATOM * 3);
    float*    dens     = (float*)(cnt8 + (size_t)TOTNATOM * NSUB);
    float*    tvv      = dens + (size_t)TOTNATOM * NB;
    float*    dip_part = tvv + (size_t)TOTNATOM * 3;
    float2*   rec      = (float2*)(dip_part + (size_t)(TOTNATOM / 16) * 3);
    float*    dipole   = (float*)d_out;

    hipLaunchKernelGGL(scatter_kernel, dim3(NMOL * NSUB), dim3(1024), 0, stream,
                       cart, shifts, species, atom_index, cnt8, rec, tv_part);
    hipLaunchKernelGGL(gather_kernel, dim3(TOTNATOM / ABLK), dim3(256), 0, stream,
                       cnt8, rec, centers, widths, c_emb, tv_part, dens, tvv);
    hipLaunchKernelGGL(nn_kernel, dim3(TOTNATOM / 16), dim3(256), 0, stream,
                       dens, tvv, W1, b1, W2, b2, dip_part);
    hipLaunchKernelGGL(dipfinal_kernel, dim3(1), dim3(128), 0, stream,
                       dip_part, dipole);
}

// Round 12
// 60.709 us; speedup vs baseline: 1.3054x; 1.0335x over previous
//
#include <hip/hip_runtime.h>

#define NMOL   32
#define NATOM  512
#define NPAIR  32768
#define NB     64
#define HIDDEN 256
#define TOTNATOM (NMOL * NATOM)
#define NSUB   8
#define CAP8   16    // records per (atom, sub-block)
#define ABLK   16    // atoms per gnn block
#define SLOTS  128   // LDS record slots per atom (= NSUB*CAP8, no overflow)

// ---------------------------------------------------------------------------
// K1 scatter: 256 blocks (mol x sub) x 1024 thr, 4 pairs/thread.
// cart+species staged in LDS; LDS-private counters -> per-block record
// segments; zero cross-XCD atomics. Block 0 also zeroes dipole (stream order
// guarantees completion before gnn's atomics).
// ---------------------------------------------------------------------------
__global__ __launch_bounds__(1024) void scatter_kernel(
    const float* __restrict__ cart, const float* __restrict__ shifts,
    const int* __restrict__ species, const int* __restrict__ atom_index,
    unsigned* __restrict__ cnt8, float2* __restrict__ rec,
    float* __restrict__ tv_part, float* __restrict__ dipole, int ndip)
{
    __shared__ float    tv_sc[NATOM * 3];   // 6 KB
    __shared__ float    s_cart[NATOM * 3];  // 6 KB
    __shared__ int      s_sp[NATOM];        // 2 KB
    __shared__ unsigned lcnt[NATOM];        // 2 KB
    const int tid = threadIdx.x;
    const int b   = blockIdx.x;
    const int mol = b >> 3;
    const int sub = b & 7;

    if (b == 0 && tid < ndip) dipole[tid] = 0.f;

    const float* cm = cart + (size_t)mol * NATOM * 3;
    const int*   sp = species + (size_t)mol * NATOM;
    for (int i = tid; i < NATOM * 3; i += 1024) { tv_sc[i] = 0.f; s_cart[i] = cm[i]; }
    if (tid < NATOM) { lcnt[tid] = 0u; s_sp[tid] = sp[tid]; }
    __syncthreads();

    const int* ai0 = atom_index + (size_t)mol * NPAIR;
    const int* ai1 = ai0 + (size_t)NMOL * NPAIR;
    const float* sh = shifts + (size_t)mol * NPAIR * 3;
    const int base = sub * 4096;

#pragma unroll
    for (int k = 0; k < 4; ++k) {
        const int p  = base + k * 1024 + tid;
        const int i0 = ai0[p];
        const int i1 = ai1[p];
        const float sx = sh[p * 3 + 0], sy = sh[p * 3 + 1], sz = sh[p * 3 + 2];
        if (!(sx > -1e10f && sy > -1e10f && sz > -1e10f)) continue;  // masked
        const float dx = s_cart[i0 * 3 + 0] - s_cart[i1 * 3 + 0] + sx;
        const float dy = s_cart[i0 * 3 + 1] - s_cart[i1 * 3 + 1] + sy;
        const float dz = s_cart[i0 * 3 + 2] - s_cart[i1 * 3 + 2] + sz;
        unsafeAtomicAdd(&tv_sc[i0 * 3 + 0], dx);        // ds_add_f32
        unsafeAtomicAdd(&tv_sc[i0 * 3 + 1], dy);
        unsafeAtomicAdd(&tv_sc[i0 * 3 + 2], dz);
        const float d = sqrtf(dx * dx + dy * dy + dz * dz + 1e-12f);
        if (d < 5.0f) {
            const float fc = 0.5f * (__cosf(0.62831853071795864769f * d) + 1.f);
            // pack spc into fc's low 3 mantissa bits (<=2^-20 rel perturbation)
            const unsigned fb = (__float_as_uint(fc) & ~7u) | (unsigned)s_sp[i1];
            const unsigned pos = atomicAdd(&lcnt[i0], 1u);   // LDS, native
            if (pos < CAP8)
                rec[((size_t)b * NATOM + i0) * CAP8 + pos] =
                    make_float2(d, __uint_as_float(fb));
        }
    }
    __syncthreads();

    if (tid < NATOM) cnt8[((size_t)mol * NATOM + tid) * NSUB + sub] = lcnt[tid];
    float* tg = tv_part + (size_t)b * NATOM * 3;
    for (int i = tid; i < NATOM * 3; i += 1024) tg[i] = tv_sc[i];
}

// ---------------------------------------------------------------------------
// K2 gnn (gather + nn fused): 1024 blocks x 256 thr, 16 atoms/block.
// Plain __launch_bounds__(256), NO min-waves hint: R8 failed at 1024thr
// (VGPR<=64 forced, w1r spilled); R10 failed with (256,4) hint (52 VGPR,
// w1r demoted to per-atom W1 L2 re-loads). Here the allocator may take
// ~110 VGPR so w1r[64] stays register-resident.
//   stage: parallel segment fetch, 128 threads copy one (atom,sub) each
//   gather: wave = 4 atoms, lane = basis, float4 LDS record stream
//   nn:     thread = hidden unit, 16 atoms from LDS density
//   dipole: 3 device atomics per block (3K total -- known fine from R1-R4)
// ---------------------------------------------------------------------------
__global__ __launch_bounds__(256) void gnn_kernel(
    const unsigned* __restrict__ cnt8, const float2* __restrict__ rec,
    const float* __restrict__ centers, const float* __restrict__ widths,
    const float* __restrict__ c_emb, const float* __restrict__ tv_part,
    const float* __restrict__ W1, const float* __restrict__ b1,
    const float* __restrict__ W2, const float* __restrict__ b2,
    float* __restrict__ dipole)
{
    __shared__ float    cemb[8 * NB];          // 2 KB
    __shared__ float2   list[ABLK][SLOTS];     // 16 KB
    __shared__ unsigned scnt[ABLK][NSUB];
    __shared__ unsigned soff[ABLK][NSUB];
    __shared__ unsigned mtot[ABLK];
    __shared__ float    dens_l[ABLK][NB];      // 4 KB
    __shared__ float    tv_l[ABLK * 3];
    __shared__ float    part[4][ABLK];

    const int tid = threadIdx.x;
    const int a0  = blockIdx.x * ABLK;
    const int mol = a0 >> 9;
    const int ra0 = a0 & 511;

    for (int i = tid; i < 8 * NB; i += 256) cemb[i] = c_emb[i];
    if (tid < ABLK * NSUB) {
        const int al = tid >> 3, s = tid & 7;
        scnt[al][s] = cnt8[(size_t)(a0 + al) * NSUB + s];   // coalesced
    }
    __syncthreads();

    if (tid < ABLK) {    // per-atom prefix over 8 segment counts + zero-pad
        unsigned o = 0;
#pragma unroll
        for (int s = 0; s < NSUB; ++s) {
            soff[tid][s] = o;
            o += min(scnt[tid][s], (unsigned)CAP8);
        }
        const unsigned mp = (o + 7u) & ~7u;    // pad to multiple of 8
        mtot[tid] = mp;
        for (unsigned k = o; k < mp; ++k) list[tid][k] = make_float2(0.f, 0.f);
    }
    __syncthreads();

    if (tid < ABLK * NSUB) {                   // 128 parallel segment copies
        const int al = tid >> 3, s = tid & 7;
        const int n = (int)min(scnt[al][s], (unsigned)CAP8);
        const float2* src = rec + ((size_t)(mol * NSUB + s) * NATOM + (ra0 + al)) * CAP8;
        float2* dst = &list[al][soff[al][s]];
        for (int k = 0; k < n; ++k) dst[k] = src[k];
    }
    if (tid < ABLK * 3) {                      // tv: sum the 8 block-partials
        const int al = tid / 3, c = tid - al * 3;
        float s = 0.f;
#pragma unroll
        for (int sb = 0; sb < NSUB; ++sb)
            s += tv_part[((size_t)(mol * NSUB + sb) * NATOM + (ra0 + al)) * 3 + c];
        tv_l[al * 3 + c] = s;
    }
    __syncthreads();

    const int lane = tid & 63;
    const int wave = tid >> 6;

    // ---- gather compute: wave handles 4 atoms ----
    {
        const float cb   = centers[lane];
        const float nwb2 = -widths[lane] * 1.4426950408889634f;   // fold log2(e)

#define REC1(dv, fv) { const unsigned f_ = __float_as_uint(fv);              \
        const float t_ = (dv) - cb;                                          \
        acc = fmaf(exp2f(nwb2 * t_ * t_) * __uint_as_float(f_ & ~7u),        \
                   cemb[((f_ & 7u) << 6) | lane], acc); }

        for (int al = wave; al < ABLK; al += 4) {
            const int m = (int)mtot[al];
            const float4* l4 = reinterpret_cast<const float4*>(list[al]);
            float acc = 0.f;
            for (int j = 0; j < m; j += 8) {   // 8 records per chunk
                const float4 q0 = l4[(j >> 1) + 0];
                const float4 q1 = l4[(j >> 1) + 1];
                const float4 q2 = l4[(j >> 1) + 2];
                const float4 q3 = l4[(j >> 1) + 3];
                REC1(q0.x, q0.y) REC1(q0.z, q0.w)
                REC1(q1.x, q1.y) REC1(q1.z, q1.w)
                REC1(q2.x, q2.y) REC1(q2.z, q2.w)
                REC1(q3.x, q3.y) REC1(q3.z, q3.w)
            }
            dens_l[al][lane] = acc;
        }
#undef REC1
    }
    __syncthreads();

    // ---- nn: thread = hidden unit ----
    {
        const int j = tid;
        float w1r[64];
#pragma unroll
        for (int q = 0; q < 64; ++q) w1r[q] = W1[q * HIDDEN + j];
        const float b1v = b1[j];
        const float w2v = W2[j];

#pragma unroll
        for (int a = 0; a < ABLK; ++a) {
            const float4* row4 = reinterpret_cast<const float4*>(dens_l[a]);
            float h0 = b1v, h1 = 0.f, h2 = 0.f, h3 = 0.f;
#pragma unroll
            for (int q = 0; q < 16; ++q) {     // ds_read_b128 broadcast
                const float4 v = row4[q];
                h0 = fmaf(v.x, w1r[q * 4 + 0], h0);
                h1 = fmaf(v.y, w1r[q * 4 + 1], h1);
                h2 = fmaf(v.z, w1r[q * 4 + 2], h2);
                h3 = fmaf(v.w, w1r[q * 4 + 3], h3);
            }
            const float h = (h0 + h1) + (h2 + h3);
            float con = (h / (1.f + __expf(-h))) * w2v;   // silu * W2
#pragma unroll
            for (int off = 32; off; off >>= 1) con += __shfl_down(con, off);
            if (lane == 0) part[wave][a] = con;
        }
        __syncthreads();

        if (tid < ABLK) {
            const int a = tid;
            const float out = part[0][a] + part[1][a] + part[2][a] + part[3][a] + b2[0];
            float px = out * tv_l[a * 3 + 0];
            float py = out * tv_l[a * 3 + 1];
            float pz = out * tv_l[a * 3 + 2];
#pragma unroll
            for (int off = 8; off; off >>= 1) {
                px += __shfl_down(px, off, 16);
                py += __shfl_down(py, off, 16);
                pz += __shfl_down(pz, off, 16);
            }
            if (a == 0) {
                unsafeAtomicAdd(&dipole[mol * 3 + 0], px);
                unsafeAtomicAdd(&dipole[mol * 3 + 1], py);
                unsafeAtomicAdd(&dipole[mol * 3 + 2], pz);
            }
        }
    }
}

// ---------------------------------------------------------------------------
extern "C" void kernel_launch(void* const* d_in, const int* in_sizes, int n_in,
                              void* d_out, int out_size, void* d_ws, size_t ws_size,
                              hipStream_t stream)
{
    const float* cart       = (const float*)d_in[0];
    const float* shifts     = (const float*)d_in[1];
    const float* centers    = (const float*)d_in[2];
    const float* widths     = (const float*)d_in[3];
    const float* c_emb      = (const float*)d_in[4];
    const float* W1         = (const float*)d_in[5];
    const float* b1         = (const float*)d_in[6];
    const float* W2         = (const float*)d_in[7];
    const float* b2         = (const float*)d_in[8];
    const int*   species    = (const int*)d_in[10];
    const int*   atom_index = (const int*)d_in[11];

    // ws: tv_part(1.5MB) | cnt8(512KB) | rec(16MB)
    float*    tv_part = (float*)d_ws;
    unsigned* cnt8    = (unsigned*)(tv_part + (size_t)NMOL * NSUB * NATOM * 3);
    float2*   rec     = (float2*)(cnt8 + (size_t)TOTNATOM * NSUB);
    float*    dipole  = (float*)d_out;

    hipLaunchKernelGGL(scatter_kernel, dim3(NMOL * NSUB), dim3(1024), 0, stream,
                       cart, shifts, species, atom_index, cnt8, rec, tv_part,
                       dipole, out_size);
    hipLaunchKernelGGL(gnn_kernel, dim3(TOTNATOM / ABLK), dim3(256), 0, stream,
                       cnt8, rec, centers, widths, c_emb, tv_part,
                       W1, b1, W2, b2, dipole);
}